// Round 4
// baseline (231.206 us; speedup 1.0000x reference)
//
#include <hip/hip_runtime.h>

#define N_NODES 100000
#define N_EDGES 300000
#define IN_DIM 256
#define NUM_CLASSES 64
#define YDIM 128   // 2 * NUM_CLASSES

typedef __attribute__((ext_vector_type(8))) short short8;
typedef __attribute__((ext_vector_type(4))) float f32x4;

// f32 -> bf16 round-to-nearest-even (inputs are normal randoms; no NaN path needed)
static __device__ __forceinline__ unsigned short f2bf(float f) {
    union { float f; unsigned u; } v; v.f = f;
    unsigned r = v.u + 0x7FFFu + ((v.u >> 16) & 1u);
    return (unsigned short)(r >> 16);
}

// Kernel A: Y[m][0:64] = x[m] @ W[0:256], Y[m][64:128] = x[m] @ W[256:512]
// == single GEMM M=100K, K=256, N=128 against Wcat, via bf16 MFMA.
// Block: 256 threads = 4 waves; 128 rows/block (wave w: rows +w*32, two 16-row subtiles).
__global__ __launch_bounds__(256) void node_gemm_mfma(const float* __restrict__ x,
                                                      const float* __restrict__ W,
                                                      float* __restrict__ Y) {
    // Wcat^T in LDS: Wt[n][k], n in [0,128), k in [0,256), bf16, XOR-swizzled. 64 KB.
    __shared__ unsigned short Wlds[YDIM * IN_DIM];

    const int t    = threadIdx.x;
    const int lane = t & 63;
    const int wv   = t >> 6;
    const int g    = lane >> 4;   // k-group 0..3
    const int ln   = lane & 15;   // row (A) / col (B,D)

    // ---- Stage Wcat^T (bf16) into LDS, coalesced global reads ----
    // thread t: n = t & 127, k-half = (t>>7)*128; 64 iterations of k-pairs.
    {
        const int n     = t & 127;
        const int kbase = (t >> 7) * 128;
        for (int i = 0; i < 64; ++i) {
            const int k = kbase + i * 2;
            float f0, f1;
            if (n < NUM_CLASSES) {
                f0 = W[(size_t)k * NUM_CLASSES + n];
                f1 = W[(size_t)(k + 1) * NUM_CLASSES + n];
            } else {
                f0 = W[(size_t)(IN_DIM + k) * NUM_CLASSES + (n - NUM_CLASSES)];
                f1 = W[(size_t)(IN_DIM + k + 1) * NUM_CLASSES + (n - NUM_CLASSES)];
            }
            const unsigned v = (unsigned)f2bf(f0) | ((unsigned)f2bf(f1) << 16);
            int addr = n * 512 + k * 2;       // byte address, b32-aligned
            addr ^= (n & 7) << 4;             // bank swizzle (consistent with reads)
            *reinterpret_cast<unsigned*>(reinterpret_cast<char*>(Wlds) + addr) = v;
        }
    }
    __syncthreads();

    const int rowbase = blockIdx.x * 128 + wv * 32;

    f32x4 acc[2][8];
#pragma unroll
    for (int s = 0; s < 2; ++s)
#pragma unroll
        for (int nt = 0; nt < 8; ++nt)
            acc[s][nt] = (f32x4){0.f, 0.f, 0.f, 0.f};

    // A-operand rows (clamped for tail block; stores are guarded below)
    const int r0 = min(rowbase + ln,      N_NODES - 1);
    const int r1 = min(rowbase + 16 + ln, N_NODES - 1);
    const float* xr0 = x + (size_t)r0 * IN_DIM;
    const float* xr1 = x + (size_t)r1 * IN_DIM;

#pragma unroll 2
    for (int kk = 0; kk < 8; ++kk) {
        const int k0 = kk * 32 + g * 8;   // this lane's contiguous-8 k range

        // A fragments: x[row][k0 .. k0+7] -> bf16x8
        short8 a0, a1;
        {
            const float4 u = *reinterpret_cast<const float4*>(xr0 + k0);
            const float4 w_ = *reinterpret_cast<const float4*>(xr0 + k0 + 4);
            a0[0] = (short)f2bf(u.x);  a0[1] = (short)f2bf(u.y);
            a0[2] = (short)f2bf(u.z);  a0[3] = (short)f2bf(u.w);
            a0[4] = (short)f2bf(w_.x); a0[5] = (short)f2bf(w_.y);
            a0[6] = (short)f2bf(w_.z); a0[7] = (short)f2bf(w_.w);
        }
        {
            const float4 u = *reinterpret_cast<const float4*>(xr1 + k0);
            const float4 w_ = *reinterpret_cast<const float4*>(xr1 + k0 + 4);
            a1[0] = (short)f2bf(u.x);  a1[1] = (short)f2bf(u.y);
            a1[2] = (short)f2bf(u.z);  a1[3] = (short)f2bf(u.w);
            a1[4] = (short)f2bf(w_.x); a1[5] = (short)f2bf(w_.y);
            a1[6] = (short)f2bf(w_.z); a1[7] = (short)f2bf(w_.w);
        }

        // B fragments: Wt[nt*16 + ln][k0 .. k0+7] via swizzled ds_read_b128
        short8 bfr[8];
#pragma unroll
        for (int nt = 0; nt < 8; ++nt) {
            const int row = nt * 16 + ln;
            int addr = row * 512 + k0 * 2;
            addr ^= (row & 7) << 4;           // same key as the write side (row&7 == ln&7)
            bfr[nt] = *reinterpret_cast<const short8*>(
                reinterpret_cast<const char*>(Wlds) + addr);
        }

#pragma unroll
        for (int nt = 0; nt < 8; ++nt) {
            acc[0][nt] = __builtin_amdgcn_mfma_f32_16x16x32_bf16(a0, bfr[nt], acc[0][nt], 0, 0, 0);
            acc[1][nt] = __builtin_amdgcn_mfma_f32_16x16x32_bf16(a1, bfr[nt], acc[1][nt], 0, 0, 0);
        }
    }

    // Store: D row = 4*g + reg (+ subtile*16), col = nt*16 + ln
#pragma unroll
    for (int s = 0; s < 2; ++s) {
#pragma unroll
        for (int r = 0; r < 4; ++r) {
            const int grow = rowbase + s * 16 + 4 * g + r;
            if (grow < N_NODES) {
                float* yrow = Y + (size_t)grow * YDIM;
#pragma unroll
                for (int nt = 0; nt < 8; ++nt)
                    yrow[nt * 16 + ln] = acc[s][nt][r];
            }
        }
    }
}

// Kernel B: edge combine. 16 lanes per edge, one float4 of the 64 outputs per lane.
// out[e][c] = Y[src[e]][c] + Y[dst[e]][64+c] + b[c]
__global__ __launch_bounds__(256) void edge_combine(const int* __restrict__ src,
                                                    const int* __restrict__ dst,
                                                    const float* __restrict__ Y,
                                                    const float* __restrict__ b,
                                                    float* __restrict__ out) {
    int t = blockIdx.x * 256 + threadIdx.x;
    int e = t >> 4;
    int part = t & 15;
    if (e >= N_EDGES) return;

    int s = src[e];
    int d = dst[e];

    float4 ys = *reinterpret_cast<const float4*>(Y + (size_t)s * YDIM + part * 4);
    float4 yd = *reinterpret_cast<const float4*>(Y + (size_t)d * YDIM + 64 + part * 4);
    float4 bv = *reinterpret_cast<const float4*>(b + part * 4);

    float4 o;
    o.x = ys.x + yd.x + bv.x;
    o.y = ys.y + yd.y + bv.y;
    o.z = ys.z + yd.z + bv.z;
    o.w = ys.w + yd.w + bv.w;

    *reinterpret_cast<float4*>(out + (size_t)e * NUM_CLASSES + part * 4) = o;
}

extern "C" void kernel_launch(void* const* d_in, const int* in_sizes, int n_in,
                              void* d_out, int out_size, void* d_ws, size_t ws_size,
                              hipStream_t stream) {
    const float* x   = (const float*)d_in[0];
    const int*   src = (const int*)d_in[1];
    const int*   dst = (const int*)d_in[2];
    const float* W   = (const float*)d_in[3];
    const float* b   = (const float*)d_in[4];
    float* out = (float*)d_out;

    // Workspace: Y = N_NODES x 128 f32 = 51.2 MB
    float* Y = (float*)d_ws;

    int blocksA = (N_NODES + 127) / 128;
    node_gemm_mfma<<<blocksA, 256, 0, stream>>>(x, W, Y);

    int blocksB = (N_EDGES * 16 + 255) / 256;
    edge_combine<<<blocksB, 256, 0, stream>>>(src, dst, Y, b, out);
}

// Round 14
// 214.526 us; speedup vs baseline: 1.0778x; 1.0778x over previous
//
#include <hip/hip_runtime.h>

#define N_NODES 100000
#define N_EDGES 300000
#define IN_DIM 256
#define NUM_CLASSES 64
#define YDIM 128   // 2 * NUM_CLASSES

typedef __attribute__((ext_vector_type(8))) short short8;
typedef __attribute__((ext_vector_type(4))) float f32x4;

static __device__ __forceinline__ unsigned short f2bf(float f) {
    union { float f; unsigned u; } v; v.f = f;
    unsigned r = v.u + 0x7FFFu + ((v.u >> 16) & 1u);   // RTNE
    return (unsigned short)(r >> 16);
}
static __device__ __forceinline__ float bf2f(unsigned short u) {
    union { unsigned u; float f; } v; v.u = ((unsigned)u) << 16;
    return v.f;
}

typedef __attribute__((address_space(3))) unsigned char lds_byte;
typedef const __attribute__((address_space(1))) unsigned char glb_byte;

// Kernel A: Y[m][0:64] = x[m]@W[:256], Y[m][64:128] = x[m]@W[256:], bf16 out.
// 256 thr = 4 waves x 16 rows = 64-row tiles; 4 tiles per block (W staged once).
// x streamed HBM->LDS via global_load_lds (double-buffered 2x8KB, one
// __syncthreads per K-step: stage(s+1) issued BEFORE compute(s), so HBM
// latency hides under compute; the barrier's vmcnt(0) drain publishes it).
// x-LDS chunk-swizzled via pre-swizzled SOURCE (linear DMA dest, rule #21).
__global__ __launch_bounds__(256) void node_gemm_mfma(const float* __restrict__ x,
                                                      const float* __restrict__ W,
                                                      unsigned short* __restrict__ Yb) {
    __shared__ unsigned short Wlds[YDIM * IN_DIM];   // 64 KB, Wcat^T [n][k] bf16, XOR-swz
    __shared__ float xb[2][2048];                    // 2 x 8KB: [64 rows][8 chunks][4 f32]

    const int t    = threadIdx.x;
    const int lane = t & 63;
    const int wv   = t >> 6;      // wave 0..3
    const int g    = lane >> 4;   // k-group 0..3
    const int ln   = lane & 15;   // A-row / B-col / D-col

    // ---- x staging geometry ----
    const int r0 = t >> 3;        // 0..31 (also stages r0+32)
    const int p  = t & 7;         // physical 16B chunk slot within row
    const int c0 = (p ^ (r0 & 7)) * 4;   // logical f32 offset ((r0+32)&7 == r0&7)
    const int blockbase = blockIdx.x * 256;

    auto stage = [&](int s, int buf) {
        const int tile = s >> 3, q = s & 7;
        const int tb = blockbase + tile * 64;
        int gr0 = tb + r0;      if (gr0 > N_NODES - 1) gr0 = N_NODES - 1;
        int gr1 = tb + r0 + 32; if (gr1 > N_NODES - 1) gr1 = N_NODES - 1;
        const float* src0 = x + (size_t)gr0 * IN_DIM + q * 32 + c0;
        const float* src1 = x + (size_t)gr1 * IN_DIM + q * 32 + c0;
        float* dst0 = &xb[buf][(r0 * 8 + p) * 4];
        float* dst1 = &xb[buf][((r0 + 32) * 8 + p) * 4];
        __builtin_amdgcn_global_load_lds((glb_byte*)src0, (lds_byte*)dst0, 16, 0, 0);
        __builtin_amdgcn_global_load_lds((glb_byte*)src1, (lds_byte*)dst1, 16, 0, 0);
    };

    stage(0, 0);   // prologue prefetch (overlaps the W-stage below)

    // ---- Stage Wcat^T (bf16) into LDS, once per block ----
    {
        const int n     = t & 127;
        const int kbase = (t >> 7) * 128;
        const unsigned swz = (unsigned)((n & 7) << 4);
#pragma unroll 4
        for (int i = 0; i < 64; ++i) {
            const int k = kbase + i * 2;
            float f0, f1;
            if (n < NUM_CLASSES) {
                f0 = W[(size_t)k * NUM_CLASSES + n];
                f1 = W[(size_t)(k + 1) * NUM_CLASSES + n];
            } else {
                f0 = W[(size_t)(IN_DIM + k) * NUM_CLASSES + (n - NUM_CLASSES)];
                f1 = W[(size_t)(IN_DIM + k + 1) * NUM_CLASSES + (n - NUM_CLASSES)];
            }
            const unsigned v = (unsigned)f2bf(f0) | ((unsigned)f2bf(f1) << 16);
            const unsigned addr = (unsigned)(n * 512 + k * 2) ^ swz;
            *reinterpret_cast<unsigned*>(reinterpret_cast<char*>(Wlds) + addr) = v;
        }
    }

    __syncthreads();   // publishes W ds_writes AND stage(0) (vmcnt+lgkm drained)

    f32x4 acc[8];
#pragma unroll
    for (int nt = 0; nt < 8; ++nt) acc[nt] = (f32x4){0.f, 0.f, 0.f, 0.f};

    const int myrow = wv * 16 + ln;   // row within 64-row tile for this lane's A-frag
    const int a_ci0 = myrow * 8 + ((2 * g)     ^ (myrow & 7));
    const int a_ci1 = myrow * 8 + ((2 * g + 1) ^ (myrow & 7));

#pragma unroll 2
    for (int s = 0; s < 32; ++s) {
        const int buf = s & 1;
        if (s < 31) stage(s + 1, buf ^ 1);   // prefetch next quarter into other buffer

        // A fragment: x[myrow][q*32 + g*8 .. +7] (two swizzled b128 reads) -> bf16x8
        const float4 af0 = *reinterpret_cast<const float4*>(&xb[buf][a_ci0 * 4]);
        const float4 af1 = *reinterpret_cast<const float4*>(&xb[buf][a_ci1 * 4]);
        short8 a;
        a[0] = (short)f2bf(af0.x); a[1] = (short)f2bf(af0.y);
        a[2] = (short)f2bf(af0.z); a[3] = (short)f2bf(af0.w);
        a[4] = (short)f2bf(af1.x); a[5] = (short)f2bf(af1.y);
        a[6] = (short)f2bf(af1.z); a[7] = (short)f2bf(af1.w);

        const int q = s & 7;
        const int kbyte = (q * 32 + g * 8) * 2;
#pragma unroll
        for (int nt = 0; nt < 8; ++nt) {
            const int n = nt * 16 + ln;
            const unsigned addr = (unsigned)(n * 512 + kbyte) ^ (unsigned)((n & 7) << 4);
            const short8 bfr = *reinterpret_cast<const short8*>(
                reinterpret_cast<const char*>(Wlds) + addr);
            acc[nt] = __builtin_amdgcn_mfma_f32_16x16x32_bf16(a, bfr, acc[nt], 0, 0, 0);
        }

        if (q == 7) {   // tile done: store Y (bf16) and reset acc
            const int rb = blockbase + (s >> 3) * 64 + wv * 16 + 4 * g;
#pragma unroll
            for (int r = 0; r < 4; ++r) {
                if (rb + r < N_NODES) {
                    unsigned short* yrow = Yb + (size_t)(rb + r) * YDIM;
#pragma unroll
                    for (int nt = 0; nt < 8; ++nt)
                        yrow[nt * 16 + ln] = f2bf(acc[nt][r]);
                }
            }
#pragma unroll
            for (int nt = 0; nt < 8; ++nt) acc[nt] = (f32x4){0.f, 0.f, 0.f, 0.f};
        }

        // One barrier per step: closes all reads of buf (so it can be re-staged
        // next iter) and drains vmcnt -> stage(s+1) is ready for iter s+1.
        __syncthreads();
    }
}

// Kernel B: out[e][c] = Y[src[e]][c] + Y[dst[e]][64+c] + b[c]; 8 lanes/edge, bf16 Y.
__global__ __launch_bounds__(256) void edge_combine(const int* __restrict__ src,
                                                    const int* __restrict__ dst,
                                                    const unsigned short* __restrict__ Yb,
                                                    const float* __restrict__ b,
                                                    float* __restrict__ out) {
    const int t = blockIdx.x * 256 + threadIdx.x;
    const int e = t >> 3;
    const int part = t & 7;
    if (e >= N_EDGES) return;

    const int s = src[e];
    const int d = dst[e];

    const short8 ys = *reinterpret_cast<const short8*>(Yb + (size_t)s * YDIM + part * 8);
    const short8 yd = *reinterpret_cast<const short8*>(Yb + (size_t)d * YDIM + 64 + part * 8);
    const float4 b0 = *reinterpret_cast<const float4*>(b + part * 8);
    const float4 b1 = *reinterpret_cast<const float4*>(b + part * 8 + 4);

    float4 o0, o1;
    o0.x = bf2f((unsigned short)ys[0]) + bf2f((unsigned short)yd[0]) + b0.x;
    o0.y = bf2f((unsigned short)ys[1]) + bf2f((unsigned short)yd[1]) + b0.y;
    o0.z = bf2f((unsigned short)ys[2]) + bf2f((unsigned short)yd[2]) + b0.z;
    o0.w = bf2f((unsigned short)ys[3]) + bf2f((unsigned short)yd[3]) + b0.w;
    o1.x = bf2f((unsigned short)ys[4]) + bf2f((unsigned short)yd[4]) + b1.x;
    o1.y = bf2f((unsigned short)ys[5]) + bf2f((unsigned short)yd[5]) + b1.y;
    o1.z = bf2f((unsigned short)ys[6]) + bf2f((unsigned short)yd[6]) + b1.z;
    o1.w = bf2f((unsigned short)ys[7]) + bf2f((unsigned short)yd[7]) + b1.w;

    float* op = out + (size_t)e * NUM_CLASSES + part * 8;
    *reinterpret_cast<float4*>(op)     = o0;
    *reinterpret_cast<float4*>(op + 4) = o1;
}

extern "C" void kernel_launch(void* const* d_in, const int* in_sizes, int n_in,
                              void* d_out, int out_size, void* d_ws, size_t ws_size,
                              hipStream_t stream) {
    const float* x   = (const float*)d_in[0];
    const int*   src = (const int*)d_in[1];
    const int*   dst = (const int*)d_in[2];
    const float* W   = (const float*)d_in[3];
    const float* b   = (const float*)d_in[4];
    float* out = (float*)d_out;

    // Workspace: Yb = N_NODES x 128 bf16 = 25.6 MB (fully rewritten every launch)
    unsigned short* Yb = (unsigned short*)d_ws;

    const int blocksA = (N_NODES + 255) / 256;   // 391 blocks x 4 tiles x 64 rows
    node_gemm_mfma<<<blocksA, 256, 0, stream>>>(x, W, Yb);

    const int blocksB = (N_EDGES * 8 + 255) / 256;
    edge_combine<<<blocksB, 256, 0, stream>>>(src, dst, Yb, b, out);
}

// Round 15
// 212.353 us; speedup vs baseline: 1.0888x; 1.0102x over previous
//
#include <hip/hip_runtime.h>

#define N_NODES 100000
#define N_EDGES 300000
#define IN_DIM 256
#define NUM_CLASSES 64
#define YDIM 128   // 2 * NUM_CLASSES

typedef __attribute__((ext_vector_type(8))) short short8;
typedef __attribute__((ext_vector_type(4))) float f32x4;

static __device__ __forceinline__ unsigned short f2bf(float f) {
    union { float f; unsigned u; } v; v.f = f;
    unsigned r = v.u + 0x7FFFu + ((v.u >> 16) & 1u);   // RTNE
    return (unsigned short)(r >> 16);
}
static __device__ __forceinline__ float bf2f(unsigned short u) {
    union { unsigned u; float f; } v; v.u = ((unsigned)u) << 16;
    return v.f;
}

typedef __attribute__((address_space(3))) unsigned char lds_byte;
typedef const __attribute__((address_space(1))) unsigned char glb_byte;

// Kernel A: Y[m][0:64] = x[m]@W[:256], Y[m][64:128] = x[m]@W[256:], bf16 out.
// 256 thr = 4 waves x 16 rows = 64-row tiles; 4 tiles per block (W staged once).
// x streamed HBM->LDS via global_load_lds, 2x8KB double buffer with COUNTED
// vmcnt(2) + raw s_barrier: stage(s+1) stays in flight ACROSS the barrier
// (round-14 post-mortem: __syncthreads' vmcnt(0) drain serialized every step
// on the just-issued prefetch -> 2000+cyc/step).  Each wave's vmcnt(2) waits
// only for its own stage(s) pair; barrier A then publishes all waves' LDS
// writes. x-LDS chunk-swizzled via pre-swizzled SOURCE (linear DMA dest).
__global__ __launch_bounds__(256) void node_gemm_mfma(const float* __restrict__ x,
                                                      const float* __restrict__ W,
                                                      unsigned short* __restrict__ Yb) {
    __shared__ unsigned short Wlds[YDIM * IN_DIM];   // 64 KB, Wcat^T [n][k] bf16, XOR-swz
    __shared__ float xb[2][2048];                    // 2 x 8KB: [64 rows][8 chunks][4 f32]

    const int t    = threadIdx.x;
    const int lane = t & 63;
    const int wv   = t >> 6;      // wave 0..3
    const int g    = lane >> 4;   // k-group 0..3
    const int ln   = lane & 15;   // A-row / B-col / D-col

    // ---- x staging geometry ----
    const int r0 = t >> 3;        // 0..31 (also stages r0+32)
    const int p  = t & 7;         // physical 16B chunk slot within row
    const int c0 = (p ^ (r0 & 7)) * 4;   // logical f32 offset ((r0+32)&7 == r0&7)
    const int blockbase = blockIdx.x * 256;

    auto stage = [&](int s, int buf) {
        const int tile = s >> 3, q = s & 7;
        const int tb = blockbase + tile * 64;
        int gr0 = tb + r0;      if (gr0 > N_NODES - 1) gr0 = N_NODES - 1;
        int gr1 = tb + r0 + 32; if (gr1 > N_NODES - 1) gr1 = N_NODES - 1;
        const float* src0 = x + (size_t)gr0 * IN_DIM + q * 32 + c0;
        const float* src1 = x + (size_t)gr1 * IN_DIM + q * 32 + c0;
        float* dst0 = &xb[buf][(r0 * 8 + p) * 4];
        float* dst1 = &xb[buf][((r0 + 32) * 8 + p) * 4];
        __builtin_amdgcn_global_load_lds((glb_byte*)src0, (lds_byte*)dst0, 16, 0, 0);
        __builtin_amdgcn_global_load_lds((glb_byte*)src1, (lds_byte*)dst1, 16, 0, 0);
    };

    stage(0, 0);   // prologue prefetch (overlaps the W-stage below)

    // ---- Stage Wcat^T (bf16) into LDS, once per block ----
    {
        const int n     = t & 127;
        const int kbase = (t >> 7) * 128;
        const unsigned swz = (unsigned)((n & 7) << 4);
#pragma unroll 4
        for (int i = 0; i < 64; ++i) {
            const int k = kbase + i * 2;
            float f0, f1;
            if (n < NUM_CLASSES) {
                f0 = W[(size_t)k * NUM_CLASSES + n];
                f1 = W[(size_t)(k + 1) * NUM_CLASSES + n];
            } else {
                f0 = W[(size_t)(IN_DIM + k) * NUM_CLASSES + (n - NUM_CLASSES)];
                f1 = W[(size_t)(IN_DIM + k + 1) * NUM_CLASSES + (n - NUM_CLASSES)];
            }
            const unsigned v = (unsigned)f2bf(f0) | ((unsigned)f2bf(f1) << 16);
            const unsigned addr = (unsigned)(n * 512 + k * 2) ^ swz;
            *reinterpret_cast<unsigned*>(reinterpret_cast<char*>(Wlds) + addr) = v;
        }
    }

    // Prologue sync: publishes W ds_writes AND stage(0) (full drain, one-time cost).
    __syncthreads();

    f32x4 acc[8];
#pragma unroll
    for (int nt = 0; nt < 8; ++nt) acc[nt] = (f32x4){0.f, 0.f, 0.f, 0.f};

    const int myrow = wv * 16 + ln;   // row within 64-row tile for this lane's A-frag
    const int a_ci0 = myrow * 8 + ((2 * g)     ^ (myrow & 7));
    const int a_ci1 = myrow * 8 + ((2 * g + 1) ^ (myrow & 7));

#pragma unroll 2
    for (int s = 0; s < 32; ++s) {
        const int buf = s & 1;
        if (s < 31) {
            stage(s + 1, buf ^ 1);
            // Wait only until 2 loads remain outstanding = this wave's stage(s)
            // pair has landed; stage(s+1) stays in flight across the barrier.
            asm volatile("s_waitcnt vmcnt(2)" ::: "memory");
        } else {
            asm volatile("s_waitcnt vmcnt(0)" ::: "memory");
        }
        __builtin_amdgcn_s_barrier();      // A: buf[s] ready for all waves
        asm volatile("" ::: "memory");

        // A fragment: x[myrow][q*32 + g*8 .. +7] (two swizzled b128 reads) -> bf16x8
        const float4 af0 = *reinterpret_cast<const float4*>(&xb[buf][a_ci0 * 4]);
        const float4 af1 = *reinterpret_cast<const float4*>(&xb[buf][a_ci1 * 4]);
        short8 a;
        a[0] = (short)f2bf(af0.x); a[1] = (short)f2bf(af0.y);
        a[2] = (short)f2bf(af0.z); a[3] = (short)f2bf(af0.w);
        a[4] = (short)f2bf(af1.x); a[5] = (short)f2bf(af1.y);
        a[6] = (short)f2bf(af1.z); a[7] = (short)f2bf(af1.w);

        const int q = s & 7;
        const int kbyte = (q * 32 + g * 8) * 2;
#pragma unroll
        for (int nt = 0; nt < 8; ++nt) {
            const int n = nt * 16 + ln;
            const unsigned addr = (unsigned)(n * 512 + kbyte) ^ (unsigned)((n & 7) << 4);
            const short8 bfr = *reinterpret_cast<const short8*>(
                reinterpret_cast<const char*>(Wlds) + addr);
            acc[nt] = __builtin_amdgcn_mfma_f32_16x16x32_bf16(a, bfr, acc[nt], 0, 0, 0);
        }

        if (q == 7) {   // tile done: store Y (bf16) and reset acc
            const int rb = blockbase + (s >> 3) * 64 + wv * 16 + 4 * g;
#pragma unroll
            for (int r = 0; r < 4; ++r) {
                if (rb + r < N_NODES) {
                    unsigned short* yrow = Yb + (size_t)(rb + r) * YDIM;
#pragma unroll
                    for (int nt = 0; nt < 8; ++nt)
                        yrow[nt * 16 + ln] = f2bf(acc[nt][r]);
                }
            }
#pragma unroll
            for (int nt = 0; nt < 8; ++nt) acc[nt] = (f32x4){0.f, 0.f, 0.f, 0.f};
        }

        asm volatile("" ::: "memory");
        __builtin_amdgcn_s_barrier();      // B: all waves done reading buf[s];
        asm volatile("" ::: "memory");     //    next iter may re-stage it
    }
}

// Kernel B: out[e][c] = Y[src[e]][c] + Y[dst[e]][64+c] + b[c]; 8 lanes/edge, bf16 Y.
__global__ __launch_bounds__(256) void edge_combine(const int* __restrict__ src,
                                                    const int* __restrict__ dst,
                                                    const unsigned short* __restrict__ Yb,
                                                    const float* __restrict__ b,
                                                    float* __restrict__ out) {
    const int t = blockIdx.x * 256 + threadIdx.x;
    const int e = t >> 3;
    const int part = t & 7;
    if (e >= N_EDGES) return;

    const int s = src[e];
    const int d = dst[e];

    const short8 ys = *reinterpret_cast<const short8*>(Yb + (size_t)s * YDIM + part * 8);
    const short8 yd = *reinterpret_cast<const short8*>(Yb + (size_t)d * YDIM + 64 + part * 8);
    const float4 b0 = *reinterpret_cast<const float4*>(b + part * 8);
    const float4 b1 = *reinterpret_cast<const float4*>(b + part * 8 + 4);

    float4 o0, o1;
    o0.x = bf2f((unsigned short)ys[0]) + bf2f((unsigned short)yd[0]) + b0.x;
    o0.y = bf2f((unsigned short)ys[1]) + bf2f((unsigned short)yd[1]) + b0.y;
    o0.z = bf2f((unsigned short)ys[2]) + bf2f((unsigned short)yd[2]) + b0.z;
    o0.w = bf2f((unsigned short)ys[3]) + bf2f((unsigned short)yd[3]) + b0.w;
    o1.x = bf2f((unsigned short)ys[4]) + bf2f((unsigned short)yd[4]) + b1.x;
    o1.y = bf2f((unsigned short)ys[5]) + bf2f((unsigned short)yd[5]) + b1.y;
    o1.z = bf2f((unsigned short)ys[6]) + bf2f((unsigned short)yd[6]) + b1.z;
    o1.w = bf2f((unsigned short)ys[7]) + bf2f((unsigned short)yd[7]) + b1.w;

    float* op = out + (size_t)e * NUM_CLASSES + part * 8;
    *reinterpret_cast<float4*>(op)     = o0;
    *reinterpret_cast<float4*>(op + 4) = o1;
}

extern "C" void kernel_launch(void* const* d_in, const int* in_sizes, int n_in,
                              void* d_out, int out_size, void* d_ws, size_t ws_size,
                              hipStream_t stream) {
    const float* x   = (const float*)d_in[0];
    const int*   src = (const int*)d_in[1];
    const int*   dst = (const int*)d_in[2];
    const float* W   = (const float*)d_in[3];
    const float* b   = (const float*)d_in[4];
    float* out = (float*)d_out;

    // Workspace: Yb = N_NODES x 128 bf16 = 25.6 MB (fully rewritten every launch)
    unsigned short* Yb = (unsigned short*)d_ws;

    const int blocksA = (N_NODES + 255) / 256;   // 391 blocks x 4 tiles x 64 rows
    node_gemm_mfma<<<blocksA, 256, 0, stream>>>(x, W, Yb);

    const int blocksB = (N_EDGES * 8 + 255) / 256;
    edge_combine<<<blocksB, 256, 0, stream>>>(src, dst, Yb, b, out);
}